// Round 1
// baseline (2383.386 us; speedup 1.0000x reference)
//
#include <hip/hip_runtime.h>
#include <hip/hip_bf16.h>
#include <math.h>

#define BB 128
#define TT 2048
#define II 64
#define HH 128
#define GG (4*HH)   // 512 gate rows

__device__ __forceinline__ float fsig(float z) {
    // 1/(1+e^-z); __expf(-inf)=0, __expf(+inf)=inf -> limits correct
    return 1.0f / (1.0f + __expf(-z));
}
__device__ __forceinline__ float ftanh(float z) {
    // tanh(z) = 1 - 2/(e^{2z}+1); correct limits at +/-inf, no inf/inf NaN
    float e = __expf(2.0f * z);
    return 1.0f - 2.0f / (e + 1.0f);
}

__global__ __launch_bounds__(GG, 2) void lstm_persist(
    const float* __restrict__ x,      // [B,T,I]
    const float* __restrict__ W_ih,   // [4H,I]
    const float* __restrict__ W_hh,   // [4H,H]
    const float* __restrict__ b_ih,   // [4H]
    const float* __restrict__ b_hh,   // [4H]
    float* __restrict__ out)          // [B,T,H]
{
    const int b = blockIdx.x;
    const int j = threadIdx.x;        // gate row 0..511: i[0,128) f[128,256) g[256,384) o[384,512)

    // ---- weights into registers (one-time; rows are 256B/512B, L2-cached, shared by all blocks)
    float wih[II];
    float whh[HH];
    {
        const float4* wr = reinterpret_cast<const float4*>(W_ih + (size_t)j * II);
        #pragma unroll
        for (int k = 0; k < II/4; ++k) {
            float4 v = wr[k];
            wih[4*k+0] = v.x; wih[4*k+1] = v.y; wih[4*k+2] = v.z; wih[4*k+3] = v.w;
        }
    }
    {
        const float4* wr = reinterpret_cast<const float4*>(W_hh + (size_t)j * HH);
        #pragma unroll
        for (int k = 0; k < HH/4; ++k) {
            float4 v = wr[k];
            whh[4*k+0] = v.x; whh[4*k+1] = v.y; whh[4*k+2] = v.z; whh[4*k+3] = v.w;
        }
    }
    const float bias = b_ih[j] + b_hh[j];

    __shared__ __align__(16) float xbuf[2][II];  // double-buffered x_t
    __shared__ __align__(16) float hbuf[HH];     // h_{t-1}, broadcast-read
    __shared__ __align__(16) float gbuf[GG];     // activated gates

    float c = 0.0f;                   // cell state, owned by threads j<128
    if (j < HH) hbuf[j] = 0.0f;

    const float4* xg = reinterpret_cast<const float4*>(x + (size_t)b * TT * II);
    if (j < II/4) {                   // 16 lanes preload x[t=0]
        reinterpret_cast<float4*>(xbuf[0])[j] = xg[j];
    }
    float* outb = out + (size_t)b * TT * HH;
    __syncthreads();

    for (int t = 0; t < TT; ++t) {
        const int cur = t & 1;

        // issue next-step x load early; LDS write deferred to after compute
        float4 xnext;
        const bool pf = (j < II/4) && (t + 1 < TT);
        if (pf) xnext = xg[(size_t)(t + 1) * (II/4) + j];

        // ---- gate row j: dot(W_ih[j], x_t) + dot(W_hh[j], h_{t-1}) + bias
        float a0 = bias, a1 = 0.f, a2 = 0.f, a3 = 0.f;
        const float4* xb = reinterpret_cast<const float4*>(xbuf[cur]);
        #pragma unroll
        for (int k = 0; k < II/4; ++k) {
            float4 v = xb[k];                 // broadcast LDS read (same addr all lanes)
            a0 += wih[4*k+0] * v.x;
            a1 += wih[4*k+1] * v.y;
            a2 += wih[4*k+2] * v.z;
            a3 += wih[4*k+3] * v.w;
        }
        const float4* hb = reinterpret_cast<const float4*>(hbuf);
        #pragma unroll
        for (int k = 0; k < HH/4; ++k) {
            float4 v = hb[k];                 // broadcast LDS read
            a0 += whh[4*k+0] * v.x;
            a1 += whh[4*k+1] * v.y;
            a2 += whh[4*k+2] * v.z;
            a3 += whh[4*k+3] * v.w;
        }
        float acc = (a0 + a1) + (a2 + a3);

        // activation: wave-uniform branch (gate-type boundaries at multiples of 128)
        float val = (j < 2*HH || j >= 3*HH) ? fsig(acc) : ftanh(acc);
        gbuf[j] = val;
        if (pf) reinterpret_cast<float4*>(xbuf[cur ^ 1])[j] = xnext;
        __syncthreads();

        // ---- state update on threads j<128 (waves 0,1)
        if (j < HH) {
            float iv = gbuf[j];
            float fv = gbuf[HH + j];
            float gv = gbuf[2*HH + j];
            float ov = gbuf[3*HH + j];
            c = fv * c + iv * gv;
            float h = ov * ftanh(c);
            hbuf[j] = h;
            outb[(size_t)t * HH + j] = h;     // coalesced 128-float store
        }
        __syncthreads();
    }
}

extern "C" void kernel_launch(void* const* d_in, const int* in_sizes, int n_in,
                              void* d_out, int out_size, void* d_ws, size_t ws_size,
                              hipStream_t stream) {
    const float* x    = (const float*)d_in[0];
    const float* W_ih = (const float*)d_in[1];
    const float* W_hh = (const float*)d_in[2];
    const float* b_ih = (const float*)d_in[3];
    const float* b_hh = (const float*)d_in[4];
    float* out = (float*)d_out;
    (void)d_ws; (void)ws_size; (void)in_sizes; (void)n_in; (void)out_size;
    hipLaunchKernelGGL(lstm_persist, dim3(BB), dim3(GG), 0, stream,
                       x, W_ih, W_hh, b_ih, b_hh, out);
}

// Round 2
// 2364.528 us; speedup vs baseline: 1.0080x; 1.0080x over previous
//
#include <hip/hip_runtime.h>
#include <hip/hip_bf16.h>
#include <math.h>

#define BB 128
#define TT 2048
#define II 64
#define HH 128
#define GG (4*HH)   // 512 gate rows

__device__ __forceinline__ float fsig(float z) {
    // 1/(1+e^-z); __expf(-inf)=0, __expf(+inf)=inf -> limits correct
    return 1.0f / (1.0f + __expf(-z));
}
__device__ __forceinline__ float ftanh(float z) {
    // tanh(z) = 1 - 2/(e^{2z}+1); correct limits at +/-inf, no inf/inf NaN
    float e = __expf(2.0f * z);
    return 1.0f - 2.0f / (e + 1.0f);
}

__global__ __launch_bounds__(GG, 2) void lstm_persist(
    const float* __restrict__ x,      // [B,T,I]
    const float* __restrict__ W_ih,   // [4H,I]
    const float* __restrict__ W_hh,   // [4H,H]
    const float* __restrict__ b_ih,   // [4H]
    const float* __restrict__ b_hh,   // [4H]
    float* __restrict__ out)          // [B,T,H]
{
    const int b = blockIdx.x;
    const int j = threadIdx.x;        // gate row 0..511: i[0,128) f[128,256) g[256,384) o[384,512)

    // ---- weights into registers (one-time)
    float wih[II];
    float whh[HH];
    {
        const float4* wr = reinterpret_cast<const float4*>(W_ih + (size_t)j * II);
        #pragma unroll
        for (int k = 0; k < II/4; ++k) {
            float4 v = wr[k];
            wih[4*k+0] = v.x; wih[4*k+1] = v.y; wih[4*k+2] = v.z; wih[4*k+3] = v.w;
        }
    }
    {
        const float4* wr = reinterpret_cast<const float4*>(W_hh + (size_t)j * HH);
        #pragma unroll
        for (int k = 0; k < HH/4; ++k) {
            float4 v = wr[k];
            whh[4*k+0] = v.x; whh[4*k+1] = v.y; whh[4*k+2] = v.z; whh[4*k+3] = v.w;
        }
    }
    float bias = b_ih[j] + b_hh[j];

    // ---- PIN weights in VGPRs: make each value an opaque asm result so the
    // register allocator cannot rematerialize the global loads inside the
    // t-loop (round-1: VGPR_Count=116 proved weights were re-fetched from L2
    // every step -> ~100 TB of L2 traffic -> 2.5 ms). 222 live regs fits the
    // 256-VGPR budget of __launch_bounds__(512,2).
    #pragma unroll
    for (int k = 0; k < II; ++k) asm volatile("" : "+v"(wih[k]));
    #pragma unroll
    for (int k = 0; k < HH; ++k) asm volatile("" : "+v"(whh[k]));
    asm volatile("" : "+v"(bias));

    __shared__ __align__(16) float xbuf[2][II];  // double-buffered x_t
    __shared__ __align__(16) float hbuf[HH];     // h_{t-1}, broadcast-read
    __shared__ __align__(16) float gbuf[GG];     // activated gates

    float c = 0.0f;                   // cell state, owned by threads j<128
    if (j < HH) hbuf[j] = 0.0f;

    const float4* xg = reinterpret_cast<const float4*>(x + (size_t)b * TT * II);
    if (j < II/4) {                   // 16 lanes preload x[t=0]
        reinterpret_cast<float4*>(xbuf[0])[j] = xg[j];
    }
    float* outb = out + (size_t)b * TT * HH;
    __syncthreads();

    for (int t = 0; t < TT; ++t) {
        const int cur = t & 1;

        // issue next-step x load early; LDS write deferred to after compute
        float4 xnext;
        const bool pf = (j < II/4) && (t + 1 < TT);
        if (pf) xnext = xg[(size_t)(t + 1) * (II/4) + j];

        // ---- gate row j: dot(W_ih[j], x_t) + dot(W_hh[j], h_{t-1}) + bias
        float a0 = bias, a1 = 0.f, a2 = 0.f, a3 = 0.f;
        const float4* xb = reinterpret_cast<const float4*>(xbuf[cur]);
        #pragma unroll
        for (int k = 0; k < II/4; ++k) {
            float4 v = xb[k];                 // broadcast LDS read (same addr all lanes)
            a0 += wih[4*k+0] * v.x;
            a1 += wih[4*k+1] * v.y;
            a2 += wih[4*k+2] * v.z;
            a3 += wih[4*k+3] * v.w;
        }
        const float4* hb = reinterpret_cast<const float4*>(hbuf);
        #pragma unroll
        for (int k = 0; k < HH/4; ++k) {
            float4 v = hb[k];                 // broadcast LDS read
            a0 += whh[4*k+0] * v.x;
            a1 += whh[4*k+1] * v.y;
            a2 += whh[4*k+2] * v.z;
            a3 += whh[4*k+3] * v.w;
        }
        float acc = (a0 + a1) + (a2 + a3);

        // activation: wave-uniform branch (gate-type boundaries at multiples of 128)
        float val = (j < 2*HH || j >= 3*HH) ? fsig(acc) : ftanh(acc);
        gbuf[j] = val;
        if (pf) reinterpret_cast<float4*>(xbuf[cur ^ 1])[j] = xnext;
        __syncthreads();

        // ---- state update on threads j<128 (waves 0,1)
        if (j < HH) {
            float iv = gbuf[j];
            float fv = gbuf[HH + j];
            float gv = gbuf[2*HH + j];
            float ov = gbuf[3*HH + j];
            c = fv * c + iv * gv;
            float h = ov * ftanh(c);
            hbuf[j] = h;
            outb[(size_t)t * HH + j] = h;     // coalesced 128-float store
        }
        __syncthreads();
    }
}

extern "C" void kernel_launch(void* const* d_in, const int* in_sizes, int n_in,
                              void* d_out, int out_size, void* d_ws, size_t ws_size,
                              hipStream_t stream) {
    const float* x    = (const float*)d_in[0];
    const float* W_ih = (const float*)d_in[1];
    const float* W_hh = (const float*)d_in[2];
    const float* b_ih = (const float*)d_in[3];
    const float* b_hh = (const float*)d_in[4];
    float* out = (float*)d_out;
    (void)d_ws; (void)ws_size; (void)in_sizes; (void)n_in; (void)out_size;
    hipLaunchKernelGGL(lstm_persist, dim3(BB), dim3(GG), 0, stream,
                       x, W_ih, W_hh, b_ih, b_hh, out);
}

// Round 3
// 2353.449 us; speedup vs baseline: 1.0127x; 1.0047x over previous
//
#include <hip/hip_runtime.h>
#include <hip/hip_bf16.h>
#include <math.h>

#define BB 128
#define TT 2048
#define II 64
#define HH 128
#define GG (4*HH)   // 512 gate rows

__device__ __forceinline__ float fsig(float z) {
    // 1/(1+e^-z); __expf(-inf)=0, __expf(+inf)=inf -> limits correct
    return 1.0f / (1.0f + __expf(-z));
}
__device__ __forceinline__ float ftanh(float z) {
    // tanh(z) = 1 - 2/(e^{2z}+1); correct limits at +/-inf, no inf/inf NaN
    float e = __expf(2.0f * z);
    return 1.0f - 2.0f / (e + 1.0f);
}

// waves_per_eu(2,2): pin the occupancy target to exactly 2 waves/EU (= the 8
// waves of one 512-thread block on a CU). Round-2 evidence: with only a MIN
// bound (__launch_bounds__(512,2)) the scheduler reduced pressure to 116 VGPR
// to chase 4 waves/SIMD, rematerializing the 192 weight floats as per-step
// global loads -> ~393 KB/step/CU of L2 traffic -> 2.4 ms. With min=max=2 the
// allocator has 256 VGPRs and no incentive to spill/remat.
__global__ __launch_bounds__(GG) __attribute__((amdgpu_waves_per_eu(2, 2)))
void lstm_persist(
    const float* __restrict__ x,      // [B,T,I]
    const float* __restrict__ W_ih,   // [4H,I]
    const float* __restrict__ W_hh,   // [4H,H]
    const float* __restrict__ b_ih,   // [4H]
    const float* __restrict__ b_hh,   // [4H]
    float* __restrict__ out)          // [B,T,H]
{
    const int b = blockIdx.x;
    const int j = threadIdx.x;        // gate row 0..511: i[0,128) f[128,256) g[256,384) o[384,512)

    // ---- weights into registers (one-time)
    float wih[II];
    float whh[HH];
    {
        const float4* wr = reinterpret_cast<const float4*>(W_ih + (size_t)j * II);
        #pragma unroll
        for (int k = 0; k < II/4; ++k) {
            float4 v = wr[k];
            wih[4*k+0] = v.x; wih[4*k+1] = v.y; wih[4*k+2] = v.z; wih[4*k+3] = v.w;
        }
    }
    {
        const float4* wr = reinterpret_cast<const float4*>(W_hh + (size_t)j * HH);
        #pragma unroll
        for (int k = 0; k < HH/4; ++k) {
            float4 v = wr[k];
            whh[4*k+0] = v.x; whh[4*k+1] = v.y; whh[4*k+2] = v.z; whh[4*k+3] = v.w;
        }
    }
    float bias = b_ih[j] + b_hh[j];

    __shared__ __align__(16) float xbuf[2][II];  // double-buffered x_t
    __shared__ __align__(16) float hbuf[HH];     // h_{t-1}, broadcast-read
    __shared__ __align__(16) float gbuf[GG];     // activated gates

    float c = 0.0f;                   // cell state, owned by threads j<128
    if (j < HH) hbuf[j] = 0.0f;

    const float4* xg = reinterpret_cast<const float4*>(x + (size_t)b * TT * II);
    if (j < II/4) {                   // 16 lanes preload x[t=0]
        reinterpret_cast<float4*>(xbuf[0])[j] = xg[j];
    }
    float* outb = out + (size_t)b * TT * HH;
    __syncthreads();

    for (int t = 0; t < TT; ++t) {
        const int cur = t & 1;

        // issue next-step x load early; LDS write deferred to after compute
        float4 xnext;
        const bool pf = (j < II/4) && (t + 1 < TT);
        if (pf) xnext = xg[(size_t)(t + 1) * (II/4) + j];

        // ---- gate row j: dot(W_ih[j], x_t) + dot(W_hh[j], h_{t-1}) + bias
        float a0 = bias, a1 = 0.f, a2 = 0.f, a3 = 0.f;
        const float4* xb = reinterpret_cast<const float4*>(xbuf[cur]);
        #pragma unroll
        for (int k = 0; k < II/4; ++k) {
            float4 v = xb[k];                 // broadcast LDS read (same addr all lanes)
            a0 += wih[4*k+0] * v.x;
            a1 += wih[4*k+1] * v.y;
            a2 += wih[4*k+2] * v.z;
            a3 += wih[4*k+3] * v.w;
        }
        const float4* hb = reinterpret_cast<const float4*>(hbuf);
        #pragma unroll
        for (int k = 0; k < HH/4; ++k) {
            float4 v = hb[k];                 // broadcast LDS read
            a0 += whh[4*k+0] * v.x;
            a1 += whh[4*k+1] * v.y;
            a2 += whh[4*k+2] * v.z;
            a3 += whh[4*k+3] * v.w;
        }
        float acc = (a0 + a1) + (a2 + a3);

        // activation: wave-uniform branch (gate-type boundaries at multiples of 128)
        float val = (j < 2*HH || j >= 3*HH) ? fsig(acc) : ftanh(acc);
        gbuf[j] = val;
        if (pf) reinterpret_cast<float4*>(xbuf[cur ^ 1])[j] = xnext;
        __syncthreads();

        // ---- state update on threads j<128 (waves 0,1)
        if (j < HH) {
            float iv = gbuf[j];
            float fv = gbuf[HH + j];
            float gv = gbuf[2*HH + j];
            float ov = gbuf[3*HH + j];
            c = fv * c + iv * gv;
            float h = ov * ftanh(c);
            hbuf[j] = h;
            outb[(size_t)t * HH + j] = h;     // coalesced 128-float store
        }
        __syncthreads();
    }
}

extern "C" void kernel_launch(void* const* d_in, const int* in_sizes, int n_in,
                              void* d_out, int out_size, void* d_ws, size_t ws_size,
                              hipStream_t stream) {
    const float* x    = (const float*)d_in[0];
    const float* W_ih = (const float*)d_in[1];
    const float* W_hh = (const float*)d_in[2];
    const float* b_ih = (const float*)d_in[3];
    const float* b_hh = (const float*)d_in[4];
    float* out = (float*)d_out;
    (void)d_ws; (void)ws_size; (void)in_sizes; (void)n_in; (void)out_size;
    hipLaunchKernelGGL(lstm_persist, dim3(BB), dim3(GG), 0, stream,
                       x, W_ih, W_hh, b_ih, b_hh, out);
}

// Round 4
// 2205.343 us; speedup vs baseline: 1.0807x; 1.0672x over previous
//
#include <hip/hip_runtime.h>
#include <math.h>

#define BB 128
#define TT 2048
#define II 64
#define HH 128
#define GG 512          // gate rows
#define EE (II + HH)    // 192 combined operand floats [x_t ; h_{t-1}]
#define CC 48           // cols per thread (192/4 col groups)
#define NQ 12           // float4 chunks per thread per row (48/4)

typedef float f32x4 __attribute__((ext_vector_type(4)));

__device__ __forceinline__ float fsig(float z) {
    return 1.0f / (1.0f + __expf(-z));
}
__device__ __forceinline__ float ftanh(float z) {
    float e = __expf(2.0f * z);
    return 1.0f - 2.0f / (e + 1.0f);
}

// intra-quad lane permute via DPP (pure VALU; avoids ds_bpermute LDS traffic)
template<int CTRL>
__device__ __forceinline__ float qperm(float v) {
    return __int_as_float(__builtin_amdgcn_mov_dpp(__float_as_int(v), CTRL, 0xf, 0xf, false));
}
#define QP_XOR1 0xB1   // quad_perm [1,0,3,2]
#define QP_XOR2 0x4E   // quad_perm [2,3,0,1]

// Opaque load: value is asm-defined, so regalloc CANNOT rematerialize the
// global load inside the t-loop (rounds 1-3: VGPR_Count=116 proved the
// compiler kept re-fetching 192 weight floats/thread/step from cache).
#define LOADQ(dst, ptr)                                                      \
    asm volatile("global_load_dwordx4 %0, %1, off\n\ts_waitcnt vmcnt(0)"     \
                 : "=&v"(dst) : "v"(ptr) : "memory")

__global__ __launch_bounds__(GG) __attribute__((amdgpu_waves_per_eu(2, 2)))
void lstm_persist(
    const float* __restrict__ x,      // [B,T,I]
    const float* __restrict__ W_ih,   // [4H,I]
    const float* __restrict__ W_hh,   // [4H,H]
    const float* __restrict__ b_ih,   // [4H]
    const float* __restrict__ b_hh,   // [4H]
    float* __restrict__ out)          // [B,T,H]
{
    const int b  = blockIdx.x;
    const int j  = threadIdx.x;
    const int rg = j >> 2;            // row group: rows 4rg..4rg+3
    const int cg = j & 3;             // col group: combined cols [48cg, 48cg+48)

    // ---- per-thread 4x48 weight tile of combined [512 x 192] matrix, pinned
    f32x4 w[4][NQ];
    #pragma unroll
    for (int r = 0; r < 4; ++r) {
        const int row = 4 * rg + r;
        #pragma unroll
        for (int k = 0; k < NQ; ++k) {
            const int cc = cg * CC + 4 * k;   // combined col, float4-aligned in both halves
            const float* p = (cc < II) ? (W_ih + (size_t)row * II + cc)
                                       : (W_hh + (size_t)row * HH + (cc - II));
            LOADQ(w[r][k], p);
        }
    }
    const float bias = b_ih[j] + b_hh[j];

    __shared__ __align__(16) float ebuf[2][EE];   // [x_t ; h_{t-1}], double-buffered
    __shared__ __align__(16) float gbuf[GG];      // activated gates

    float c = 0.0f;                   // cell state, threads j<128
    if (j < HH) ebuf[0][II + j] = 0.0f;

    const f32x4* xg = reinterpret_cast<const f32x4*>(x + (size_t)b * TT * II);
    if (j < II / 4) reinterpret_cast<f32x4*>(&ebuf[0][0])[j] = xg[j];
    float* outb = out + (size_t)b * TT * HH;
    __syncthreads();

    for (int t = 0; t < TT; ++t) {
        const int cur = t & 1, nxt = cur ^ 1;

        // prefetch x_{t+1}; LDS write deferred to after the FMA block
        f32x4 xnext;
        const bool pf = (j < II / 4) && (t + 1 < TT);
        if (pf) xnext = xg[(size_t)(t + 1) * (II / 4) + j];

        // ---- partial dot: rows 4rg..4rg+3, cols [48cg,48cg+48) of [x;h]
        const f32x4* eb = reinterpret_cast<const f32x4*>(&ebuf[cur][0]) + cg * NQ;
        float a0 = 0.f, a1 = 0.f, a2 = 0.f, a3 = 0.f;
        #pragma unroll
        for (int k = 0; k < NQ; ++k) {
            f32x4 v = eb[k];   // 4 distinct addrs/wave, 16-lane broadcast, 2-way bank alias (free)
            a0 += w[0][k][0]*v[0] + w[0][k][1]*v[1] + w[0][k][2]*v[2] + w[0][k][3]*v[3];
            a1 += w[1][k][0]*v[0] + w[1][k][1]*v[1] + w[1][k][2]*v[2] + w[1][k][3]*v[3];
            a2 += w[2][k][0]*v[0] + w[2][k][1]*v[1] + w[2][k][2]*v[2] + w[2][k][3]*v[3];
            a3 += w[3][k][0]*v[0] + w[3][k][1]*v[1] + w[3][k][2]*v[2] + w[3][k][3]*v[3];
        }

        // ---- reduce across the 4 col-group lanes (DPP butterfly, all-VALU)
        a0 += qperm<QP_XOR1>(a0); a0 += qperm<QP_XOR2>(a0);
        a1 += qperm<QP_XOR1>(a1); a1 += qperm<QP_XOR2>(a1);
        a2 += qperm<QP_XOR1>(a2); a2 += qperm<QP_XOR2>(a2);
        a3 += qperm<QP_XOR1>(a3); a3 += qperm<QP_XOR2>(a3);
        // lane cg takes row 4rg+cg == j  (compile-time-indexed select, no scratch)
        float acc = (cg == 0) ? a0 : (cg == 1) ? a1 : (cg == 2) ? a2 : a3;
        acc += bias;

        // activation: rows [0,256)∪[384,512) sigmoid, [256,384) tanh — wave-uniform
        float val = (j < 2 * HH || j >= 3 * HH) ? fsig(acc) : ftanh(acc);
        gbuf[j] = val;
        if (pf) reinterpret_cast<f32x4*>(&ebuf[nxt][0])[j] = xnext;
        __syncthreads();

        // ---- state update on threads j<128
        if (j < HH) {
            float iv = gbuf[j];
            float fv = gbuf[HH + j];
            float gv = gbuf[2 * HH + j];
            float ov = gbuf[3 * HH + j];
            c = fv * c + iv * gv;
            float h = ov * ftanh(c);
            ebuf[nxt][II + j] = h;
            outb[(size_t)t * HH + j] = h;     // coalesced 512B store
        }
        __syncthreads();
    }
}

extern "C" void kernel_launch(void* const* d_in, const int* in_sizes, int n_in,
                              void* d_out, int out_size, void* d_ws, size_t ws_size,
                              hipStream_t stream) {
    const float* x    = (const float*)d_in[0];
    const float* W_ih = (const float*)d_in[1];
    const float* W_hh = (const float*)d_in[2];
    const float* b_ih = (const float*)d_in[3];
    const float* b_hh = (const float*)d_in[4];
    float* out = (float*)d_out;
    (void)d_ws; (void)ws_size; (void)in_sizes; (void)n_in; (void)out_size;
    hipLaunchKernelGGL(lstm_persist, dim3(BB), dim3(GG), 0, stream,
                       x, W_ih, W_hh, b_ih, b_hh, out);
}

// Round 5
// 1637.051 us; speedup vs baseline: 1.4559x; 1.3471x over previous
//
#include <hip/hip_runtime.h>
#include <math.h>

#define BB 128
#define TT 2048
#define II 64
#define HH 128
#define GG 512          // gate rows
#define EE (II + HH)    // 192 combined operand values [x_t ; h_{t-1}]

typedef _Float16 h2 __attribute__((ext_vector_type(2)));
typedef _Float16 h4 __attribute__((ext_vector_type(4)));
typedef _Float16 h8 __attribute__((ext_vector_type(8)));

__device__ __forceinline__ float fsig(float z) {
    return 1.0f / (1.0f + __expf(-z));
}
__device__ __forceinline__ float ftanh(float z) {
    float e = __expf(2.0f * z);
    return 1.0f - 2.0f / (e + 1.0f);
}

// intra-quad lane permute via DPP (pure VALU)
template<int CTRL>
__device__ __forceinline__ float qperm(float v) {
    return __int_as_float(__builtin_amdgcn_mov_dpp(__float_as_int(v), CTRL, 0xf, 0xf, false));
}
#define QP_XOR1 0xB1   // quad_perm [1,0,3,2]
#define QP_XOR2 0x4E   // quad_perm [2,3,0,1]

// fp16 weights: 4x48 tile = 96 VGPRs/thread (vs 192 f32 that spilled to AGPR
// in rounds 1-4). fdot2 = 2 MAC/instr with exact-f32 products; only error
// source is f16 quantization of W, x, h. Gate math / c / h / out stay f32.
__global__ __launch_bounds__(GG) __attribute__((amdgpu_waves_per_eu(2, 2)))
void lstm_persist(
    const float* __restrict__ x,      // [B,T,I]
    const float* __restrict__ W_ih,   // [4H,I]
    const float* __restrict__ W_hh,   // [4H,H]
    const float* __restrict__ b_ih,   // [4H]
    const float* __restrict__ b_hh,   // [4H]
    float* __restrict__ out)          // [B,T,H]
{
    const int b  = blockIdx.x;
    const int j  = threadIdx.x;
    const int rg = j >> 2;            // rows 4rg..4rg+3
    const int cg = j & 3;             // combined cols [48cg, 48cg+48)

    // ---- per-thread 4x48 weight tile, converted f32->f16 once (load+cvt+pack
    // chain is not trivially rematerializable -> stays register-resident)
    h2 w2[4][24];
    #pragma unroll
    for (int r = 0; r < 4; ++r) {
        const int row = 4 * rg + r;
        #pragma unroll
        for (int k = 0; k < 12; ++k) {
            const int cc = cg * 48 + 4 * k;   // float4-aligned; never straddles the 64-boundary
            const float* p = (cc < II) ? (W_ih + (size_t)row * II + cc)
                                       : (W_hh + (size_t)row * HH + (cc - II));
            const float4 v = *reinterpret_cast<const float4*>(p);
            h2 lo; lo[0] = (_Float16)v.x; lo[1] = (_Float16)v.y;
            h2 hi; hi[0] = (_Float16)v.z; hi[1] = (_Float16)v.w;
            w2[r][2 * k]     = lo;
            w2[r][2 * k + 1] = hi;
        }
    }
    const float bias = b_ih[j] + b_hh[j];

    __shared__ __align__(16) _Float16 ebuf[2][EE];  // [x_t ; h_{t-1}] in f16, dbuf
    __shared__ __align__(16) float gbuf[GG];        // activated gates (f32)

    float c = 0.0f;                   // cell state, threads j<128 (f32)
    if (j < HH) ebuf[0][II + j] = (_Float16)0.0f;

    const float4* xg = reinterpret_cast<const float4*>(x + (size_t)b * TT * II);
    if (j < II / 4) {                 // 16 lanes: load + convert x[t=0]
        float4 v = xg[j];
        h4 q; q[0] = (_Float16)v.x; q[1] = (_Float16)v.y;
              q[2] = (_Float16)v.z; q[3] = (_Float16)v.w;
        reinterpret_cast<h4*>(&ebuf[0][0])[j] = q;
    }
    float* outb = out + (size_t)b * TT * HH;
    __syncthreads();

    for (int t = 0; t < TT; ++t) {
        const int cur = t & 1, nxt = cur ^ 1;

        // prefetch x_{t+1} (f32); convert + LDS-write deferred past the FMAs
        float4 xnext;
        const bool pf = (j < II / 4) && (t + 1 < TT);
        if (pf) xnext = xg[(size_t)(t + 1) * (II / 4) + j];

        // ---- partial dots: rows 4rg..4rg+3 over cols [48cg,48cg+48)
        const h8* eb = reinterpret_cast<const h8*>(&ebuf[cur][0]) + cg * 6;
        float a0 = 0.f, a1 = 0.f, a2 = 0.f, a3 = 0.f;
        #pragma unroll
        for (int k = 0; k < 6; ++k) {
            h8 v = eb[k];             // 16B LDS read; h2 extracts are sub-register (free)
            h2 p0, p1, p2, p3;
            p0[0] = v[0]; p0[1] = v[1];
            p1[0] = v[2]; p1[1] = v[3];
            p2[0] = v[4]; p2[1] = v[5];
            p3[0] = v[6]; p3[1] = v[7];
            a0 = __builtin_amdgcn_fdot2(w2[0][4*k+0], p0, a0, false);
            a0 = __builtin_amdgcn_fdot2(w2[0][4*k+1], p1, a0, false);
            a0 = __builtin_amdgcn_fdot2(w2[0][4*k+2], p2, a0, false);
            a0 = __builtin_amdgcn_fdot2(w2[0][4*k+3], p3, a0, false);
            a1 = __builtin_amdgcn_fdot2(w2[1][4*k+0], p0, a1, false);
            a1 = __builtin_amdgcn_fdot2(w2[1][4*k+1], p1, a1, false);
            a1 = __builtin_amdgcn_fdot2(w2[1][4*k+2], p2, a1, false);
            a1 = __builtin_amdgcn_fdot2(w2[1][4*k+3], p3, a1, false);
            a2 = __builtin_amdgcn_fdot2(w2[2][4*k+0], p0, a2, false);
            a2 = __builtin_amdgcn_fdot2(w2[2][4*k+1], p1, a2, false);
            a2 = __builtin_amdgcn_fdot2(w2[2][4*k+2], p2, a2, false);
            a2 = __builtin_amdgcn_fdot2(w2[2][4*k+3], p3, a2, false);
            a3 = __builtin_amdgcn_fdot2(w2[3][4*k+0], p0, a3, false);
            a3 = __builtin_amdgcn_fdot2(w2[3][4*k+1], p1, a3, false);
            a3 = __builtin_amdgcn_fdot2(w2[3][4*k+2], p2, a3, false);
            a3 = __builtin_amdgcn_fdot2(w2[3][4*k+3], p3, a3, false);
        }

        // ---- reduce across the 4 col-group lanes (DPP butterfly)
        a0 += qperm<QP_XOR1>(a0); a0 += qperm<QP_XOR2>(a0);
        a1 += qperm<QP_XOR1>(a1); a1 += qperm<QP_XOR2>(a1);
        a2 += qperm<QP_XOR1>(a2); a2 += qperm<QP_XOR2>(a2);
        a3 += qperm<QP_XOR1>(a3); a3 += qperm<QP_XOR2>(a3);
        float acc = (cg == 0) ? a0 : (cg == 1) ? a1 : (cg == 2) ? a2 : a3;
        acc += bias;

        // activation: rows [0,256)∪[384,512) sigmoid, [256,384) tanh
        float val = (j < 2 * HH || j >= 3 * HH) ? fsig(acc) : ftanh(acc);
        gbuf[j] = val;
        if (pf) {
            h4 q; q[0] = (_Float16)xnext.x; q[1] = (_Float16)xnext.y;
                  q[2] = (_Float16)xnext.z; q[3] = (_Float16)xnext.w;
            reinterpret_cast<h4*>(&ebuf[nxt][0])[j] = q;
        }
        __syncthreads();

        // ---- state update on threads j<128 (full f32)
        if (j < HH) {
            float iv = gbuf[j];
            float fv = gbuf[HH + j];
            float gv = gbuf[2 * HH + j];
            float ov = gbuf[3 * HH + j];
            c = fv * c + iv * gv;
            float h = ov * ftanh(c);
            ebuf[nxt][II + j] = (_Float16)h;  // f16 operand copy for next step
            outb[(size_t)t * HH + j] = h;     // f32 output, coalesced
        }
        __syncthreads();
    }
}

extern "C" void kernel_launch(void* const* d_in, const int* in_sizes, int n_in,
                              void* d_out, int out_size, void* d_ws, size_t ws_size,
                              hipStream_t stream) {
    const float* x    = (const float*)d_in[0];
    const float* W_ih = (const float*)d_in[1];
    const float* W_hh = (const float*)d_in[2];
    const float* b_ih = (const float*)d_in[3];
    const float* b_hh = (const float*)d_in[4];
    float* out = (float*)d_out;
    (void)d_ws; (void)ws_size; (void)in_sizes; (void)n_in; (void)out_size;
    hipLaunchKernelGGL(lstm_persist, dim3(BB), dim3(GG), 0, stream,
                       x, W_ih, W_hh, b_ih, b_hh, out);
}

// Round 6
// 1491.804 us; speedup vs baseline: 1.5977x; 1.0974x over previous
//
#include <hip/hip_runtime.h>
#include <math.h>

#define BB 128
#define TT 2048
#define II 64
#define HH 128
#define EE (II + HH)    // 192 combined operand values [x_t ; h_{t-1}]

typedef _Float16 h2v __attribute__((ext_vector_type(2)));
typedef _Float16 h4v __attribute__((ext_vector_type(4)));
typedef _Float16 h8v __attribute__((ext_vector_type(8)));

// intra-quad lane permute via DPP (pure VALU)
template<int CTRL>
__device__ __forceinline__ float qperm(float v) {
    return __int_as_float(__builtin_amdgcn_mov_dpp(__float_as_int(v), CTRL, 0xf, 0xf, false));
}
#define QP_XOR1 0xB1   // quad_perm [1,0,3,2]
#define QP_XOR2 0x4E   // quad_perm [2,3,0,1]
#define QP_BC0  0x00   // quad_perm [0,0,0,0]
#define QP_BC1  0x55   // quad_perm [1,1,1,1]
#define QP_BC2  0xAA   // quad_perm [2,2,2,2]
#define QP_BC3  0xFF   // quad_perm [3,3,3,3]

// Round-6 structure: thread (m,cg) owns ALL FOUR gate rows of h-element m
// over col chunk [48cg,48cg+48). Quad butterfly gives every lane all four
// gate sums -> activation + c/h update happen in-register in the same quad.
// Deletes gbuf, both gate LDS round-trips, the 2-wave serial section, and
// one of the two per-step barriers (rounds 1-5: ~2/3 of step time was that
// serial path, VALUBusy_active only ~54%).
__global__ __launch_bounds__(512) __attribute__((amdgpu_waves_per_eu(2, 2)))
void lstm_persist(
    const float* __restrict__ x,      // [B,T,I]
    const float* __restrict__ W_ih,   // [4H,I]
    const float* __restrict__ W_hh,   // [4H,H]
    const float* __restrict__ b_ih,   // [4H]
    const float* __restrict__ b_hh,   // [4H]
    float* __restrict__ out)          // [B,T,H]
{
    const int b  = blockIdx.x;
    const int j  = threadIdx.x;
    const int m  = j >> 2;            // h-element 0..127
    const int cg = j & 3;             // col group: combined cols [48cg, 48cg+48)

    // ---- per-thread weight tile: rows {m,128+m,256+m,384+m} (= gates i,f,g,o
    // of element m) x 48 cols, f32->f16 once (96 VGPRs; round-5 proved this
    // pattern stays register-resident: VGPR=112, no per-step re-fetch)
    h2v w2[4][24];
    #pragma unroll
    for (int r = 0; r < 4; ++r) {
        const int row = r * HH + m;
        #pragma unroll
        for (int k = 0; k < 12; ++k) {
            const int cc = cg * 48 + 4 * k;   // float4-aligned; never straddles the 64-boundary
            const float* p = (cc < II) ? (W_ih + (size_t)row * II + cc)
                                       : (W_hh + (size_t)row * HH + (cc - II));
            const float4 v = *reinterpret_cast<const float4*>(p);
            h2v lo; lo[0] = (_Float16)v.x; lo[1] = (_Float16)v.y;
            h2v hi; hi[0] = (_Float16)v.z; hi[1] = (_Float16)v.w;
            w2[r][2 * k]     = lo;
            w2[r][2 * k + 1] = hi;
        }
    }
    // lane cg activates gate cg (row cg*128+m) -> needs only that row's bias
    const int brow = cg * HH + m;
    const float bias = b_ih[brow] + b_hh[brow];

    __shared__ __align__(16) _Float16 ebuf[2][EE];  // [x_t ; h_{t-1}] f16, dbuf

    float c = 0.0f;                   // cell state, replicated across the quad
    if (cg == 0) ebuf[0][II + m] = (_Float16)0.0f;

    const float4* xg = reinterpret_cast<const float4*>(x + (size_t)b * TT * II);
    if (j < II / 4) {                 // 16 lanes: load + convert x[t=0]
        float4 v = xg[j];
        h4v q; q[0] = (_Float16)v.x; q[1] = (_Float16)v.y;
               q[2] = (_Float16)v.z; q[3] = (_Float16)v.w;
        reinterpret_cast<h4v*>(&ebuf[0][0])[j] = q;
    }
    float* outb = out + (size_t)b * TT * HH;
    __syncthreads();

#define STEP(CUR, NXT, T)                                                     \
    {                                                                         \
        float4 xnext;                                                         \
        const bool pf = (j < II / 4) && ((T) + 1 < TT);                       \
        if (pf) xnext = xg[(size_t)((T) + 1) * (II / 4) + j];                 \
        const h8v* eb = reinterpret_cast<const h8v*>(&ebuf[CUR][cg * 48]);    \
        float a0 = 0.f, a1 = 0.f, a2 = 0.f, a3 = 0.f;                         \
        _Pragma("unroll")                                                     \
        for (int k = 0; k < 6; ++k) {                                         \
            h8v v = eb[k];                                                    \
            h2v p0; p0[0] = v[0]; p0[1] = v[1];                               \
            h2v p1; p1[0] = v[2]; p1[1] = v[3];                               \
            h2v p2; p2[0] = v[4]; p2[1] = v[5];                               \
            h2v p3; p3[0] = v[6]; p3[1] = v[7];                               \
            a0 = __builtin_amdgcn_fdot2(w2[0][4*k+0], p0, a0, false);         \
            a0 = __builtin_amdgcn_fdot2(w2[0][4*k+1], p1, a0, false);         \
            a0 = __builtin_amdgcn_fdot2(w2[0][4*k+2], p2, a0, false);         \
            a0 = __builtin_amdgcn_fdot2(w2[0][4*k+3], p3, a0, false);         \
            a1 = __builtin_amdgcn_fdot2(w2[1][4*k+0], p0, a1, false);         \
            a1 = __builtin_amdgcn_fdot2(w2[1][4*k+1], p1, a1, false);         \
            a1 = __builtin_amdgcn_fdot2(w2[1][4*k+2], p2, a1, false);         \
            a1 = __builtin_amdgcn_fdot2(w2[1][4*k+3], p3, a1, false);         \
            a2 = __builtin_amdgcn_fdot2(w2[2][4*k+0], p0, a2, false);         \
            a2 = __builtin_amdgcn_fdot2(w2[2][4*k+1], p1, a2, false);         \
            a2 = __builtin_amdgcn_fdot2(w2[2][4*k+2], p2, a2, false);         \
            a2 = __builtin_amdgcn_fdot2(w2[2][4*k+3], p3, a2, false);         \
            a3 = __builtin_amdgcn_fdot2(w2[3][4*k+0], p0, a3, false);         \
            a3 = __builtin_amdgcn_fdot2(w2[3][4*k+1], p1, a3, false);         \
            a3 = __builtin_amdgcn_fdot2(w2[3][4*k+2], p2, a3, false);         \
            a3 = __builtin_amdgcn_fdot2(w2[3][4*k+3], p3, a3, false);         \
        }                                                                     \
        /* quad butterfly: every lane gets all four gate sums */              \
        a0 += qperm<QP_XOR1>(a0); a0 += qperm<QP_XOR2>(a0);                   \
        a1 += qperm<QP_XOR1>(a1); a1 += qperm<QP_XOR2>(a1);                   \
        a2 += qperm<QP_XOR1>(a2); a2 += qperm<QP_XOR2>(a2);                   \
        a3 += qperm<QP_XOR1>(a3); a3 += qperm<QP_XOR2>(a3);                   \
        /* lane cg activates its own gate (tanh = 2*sig(2z)-1, branchless) */ \
        float acc = (cg == 0) ? a0 : (cg == 1) ? a1 : (cg == 2) ? a2 : a3;    \
        acc += bias;                                                          \
        const float zz = (cg == 2) ? 2.0f * acc : acc;                        \
        const float s  = 1.0f / (1.0f + __expf(-zz));                         \
        const float val = (cg == 2) ? 2.0f * s - 1.0f : s;                    \
        const float iv = qperm<QP_BC0>(val);                                  \
        const float fv = qperm<QP_BC1>(val);                                  \
        const float gv = qperm<QP_BC2>(val);                                  \
        const float ov = qperm<QP_BC3>(val);                                  \
        c = fv * c + iv * gv;        /* replicated, bitwise-identical */      \
        const float e2 = __expf(2.0f * c);                                    \
        const float th = 1.0f - 2.0f / (e2 + 1.0f);                           \
        const float h = ov * th;                                              \
        if (cg == 0) {                                                        \
            ebuf[NXT][II + m] = (_Float16)h;                                  \
            outb[(size_t)(T) * HH + m] = h;                                   \
        }                                                                     \
        if (pf) {                                                             \
            h4v q; q[0] = (_Float16)xnext.x; q[1] = (_Float16)xnext.y;        \
                   q[2] = (_Float16)xnext.z; q[3] = (_Float16)xnext.w;        \
            reinterpret_cast<h4v*>(&ebuf[NXT][0])[j] = q;                     \
        }                                                                     \
        __syncthreads();                                                      \
    }

    for (int t = 0; t < TT; t += 2) {
        STEP(0, 1, t);
        STEP(1, 0, t + 1);
    }
#undef STEP
}

extern "C" void kernel_launch(void* const* d_in, const int* in_sizes, int n_in,
                              void* d_out, int out_size, void* d_ws, size_t ws_size,
                              hipStream_t stream) {
    const float* x    = (const float*)d_in[0];
    const float* W_ih = (const float*)d_in[1];
    const float* W_hh = (const float*)d_in[2];
    const float* b_ih = (const float*)d_in[3];
    const float* b_hh = (const float*)d_in[4];
    float* out = (float*)d_out;
    (void)d_ws; (void)ws_size; (void)in_sizes; (void)n_in; (void)out_size;
    hipLaunchKernelGGL(lstm_persist, dim3(BB), dim3(512), 0, stream,
                       x, W_ih, W_hh, b_ih, b_hh, out);
}

// Round 7
// 1484.109 us; speedup vs baseline: 1.6059x; 1.0052x over previous
//
#include <hip/hip_runtime.h>
#include <math.h>

#define BB 128
#define TT 2048
#define II 64
#define HH 128
#define EE (II + HH)    // 192 combined operand values [x_t ; h_{t-1}]

typedef _Float16 h2v __attribute__((ext_vector_type(2)));
typedef _Float16 h4v __attribute__((ext_vector_type(4)));
typedef _Float16 h8v __attribute__((ext_vector_type(8)));

// intra-quad lane permute via DPP (pure VALU)
template<int CTRL>
__device__ __forceinline__ float qperm(float v) {
    return __int_as_float(__builtin_amdgcn_mov_dpp(__float_as_int(v), CTRL, 0xf, 0xf, false));
}
#define QP_XOR1 0xB1   // quad_perm [1,0,3,2]
#define QP_XOR2 0x4E   // quad_perm [2,3,0,1]
#define QP_BC0  0x00   // quad_perm [0,0,0,0]
#define QP_BC1  0x55   // quad_perm [1,1,1,1]
#define QP_BC2  0xAA   // quad_perm [2,2,2,2]
#define QP_BC3  0xFF   // quad_perm [3,3,3,3]

// Round-7: depth-4 x prefetch. Round-6 evidence: VALUBusy 35% (70% active),
// ~1100 cyc/step of stall; the x global load (L2/HBM miss ~900 cyc) was
// issued and consumed within the same step -> wave 0 stalled on vmcnt before
// the barrier every step. Now x_{t+1} is loaded 4 steps ahead (~3000 cyc of
// cover) in 4 statically-rotated pending registers (loop unrolled by 4).
__global__ __launch_bounds__(512) __attribute__((amdgpu_waves_per_eu(2, 2)))
void lstm_persist(
    const float* __restrict__ x,      // [B,T,I]
    const float* __restrict__ W_ih,   // [4H,I]
    const float* __restrict__ W_hh,   // [4H,H]
    const float* __restrict__ b_ih,   // [4H]
    const float* __restrict__ b_hh,   // [4H]
    float* __restrict__ out)          // [B,T,H]
{
    const int b  = blockIdx.x;
    const int j  = threadIdx.x;
    const int m  = j >> 2;            // h-element 0..127
    const int cg = j & 3;             // col group: combined cols [48cg, 48cg+48)

    // ---- per-thread weight tile: rows {m,128+m,256+m,384+m} x 48 cols, f16
    h2v w2[4][24];
    #pragma unroll
    for (int r = 0; r < 4; ++r) {
        const int row = r * HH + m;
        #pragma unroll
        for (int k = 0; k < 12; ++k) {
            const int cc = cg * 48 + 4 * k;
            const float* p = (cc < II) ? (W_ih + (size_t)row * II + cc)
                                       : (W_hh + (size_t)row * HH + (cc - II));
            const float4 v = *reinterpret_cast<const float4*>(p);
            h2v lo; lo[0] = (_Float16)v.x; lo[1] = (_Float16)v.y;
            h2v hi; hi[0] = (_Float16)v.z; hi[1] = (_Float16)v.w;
            w2[r][2 * k]     = lo;
            w2[r][2 * k + 1] = hi;
        }
    }
    const int brow = cg * HH + m;
    const float bias = b_ih[brow] + b_hh[brow];

    __shared__ __align__(16) _Float16 ebuf[2][EE];  // [x_t ; h_{t-1}] f16, dbuf

    float c = 0.0f;                   // cell state, replicated across the quad
    if (cg == 0) ebuf[0][II + m] = (_Float16)0.0f;

    const float4* xg = reinterpret_cast<const float4*>(x + (size_t)b * TT * II);
    float4 xq0, xq1, xq2, xq3;        // pending x for t+1..t+4 (16 lanes)
    if (j < II / 4) {
        float4 v = xg[j];             // x[t=0] -> LDS now
        h4v q; q[0] = (_Float16)v.x; q[1] = (_Float16)v.y;
               q[2] = (_Float16)v.z; q[3] = (_Float16)v.w;
        reinterpret_cast<h4v*>(&ebuf[0][0])[j] = q;
        xq0 = xg[1 * (II / 4) + j];
        xq1 = xg[2 * (II / 4) + j];
        xq2 = xg[3 * (II / 4) + j];
        xq3 = xg[4 * (II / 4) + j];
    }
    float* outb = out + (size_t)b * TT * HH;
    __syncthreads();

#define STEP(CUR, NXT, T, XQ)                                                 \
    {                                                                         \
        /* x_{T+1}: loaded 4 steps ago -> convert + LDS write at step TOP */  \
        if (j < II / 4) {                                                     \
            h4v q; q[0] = (_Float16)XQ.x; q[1] = (_Float16)XQ.y;              \
                   q[2] = (_Float16)XQ.z; q[3] = (_Float16)XQ.w;              \
            reinterpret_cast<h4v*>(&ebuf[NXT][0])[j] = q;                     \
            if ((T) + 5 < TT)                                                 \
                XQ = xg[(size_t)((T) + 5) * (II / 4) + j];                    \
        }                                                                     \
        const h8v* eb = reinterpret_cast<const h8v*>(&ebuf[CUR][cg * 48]);    \
        float a0 = 0.f, a1 = 0.f, a2 = 0.f, a3 = 0.f;                         \
        _Pragma("unroll")                                                     \
        for (int k = 0; k < 6; ++k) {                                         \
            h8v v = eb[k];                                                    \
            h2v p0; p0[0] = v[0]; p0[1] = v[1];                               \
            h2v p1; p1[0] = v[2]; p1[1] = v[3];                               \
            h2v p2; p2[0] = v[4]; p2[1] = v[5];                               \
            h2v p3; p3[0] = v[6]; p3[1] = v[7];                               \
            a0 = __builtin_amdgcn_fdot2(w2[0][4*k+0], p0, a0, false);         \
            a0 = __builtin_amdgcn_fdot2(w2[0][4*k+1], p1, a0, false);         \
            a0 = __builtin_amdgcn_fdot2(w2[0][4*k+2], p2, a0, false);         \
            a0 = __builtin_amdgcn_fdot2(w2[0][4*k+3], p3, a0, false);         \
            a1 = __builtin_amdgcn_fdot2(w2[1][4*k+0], p0, a1, false);         \
            a1 = __builtin_amdgcn_fdot2(w2[1][4*k+1], p1, a1, false);         \
            a1 = __builtin_amdgcn_fdot2(w2[1][4*k+2], p2, a1, false);         \
            a1 = __builtin_amdgcn_fdot2(w2[1][4*k+3], p3, a1, false);         \
            a2 = __builtin_amdgcn_fdot2(w2[2][4*k+0], p0, a2, false);         \
            a2 = __builtin_amdgcn_fdot2(w2[2][4*k+1], p1, a2, false);         \
            a2 = __builtin_amdgcn_fdot2(w2[2][4*k+2], p2, a2, false);         \
            a2 = __builtin_amdgcn_fdot2(w2[2][4*k+3], p3, a2, false);         \
            a3 = __builtin_amdgcn_fdot2(w2[3][4*k+0], p0, a3, false);         \
            a3 = __builtin_amdgcn_fdot2(w2[3][4*k+1], p1, a3, false);         \
            a3 = __builtin_amdgcn_fdot2(w2[3][4*k+2], p2, a3, false);         \
            a3 = __builtin_amdgcn_fdot2(w2[3][4*k+3], p3, a3, false);         \
        }                                                                     \
        /* quad butterfly: every lane gets all four gate sums */              \
        a0 += qperm<QP_XOR1>(a0); a0 += qperm<QP_XOR2>(a0);                   \
        a1 += qperm<QP_XOR1>(a1); a1 += qperm<QP_XOR2>(a1);                   \
        a2 += qperm<QP_XOR1>(a2); a2 += qperm<QP_XOR2>(a2);                   \
        a3 += qperm<QP_XOR1>(a3); a3 += qperm<QP_XOR2>(a3);                   \
        /* lane cg activates its own gate (tanh = 2*sig(2z)-1, branchless) */ \
        float acc = (cg == 0) ? a0 : (cg == 1) ? a1 : (cg == 2) ? a2 : a3;    \
        acc += bias;                                                          \
        const float zz = (cg == 2) ? 2.0f * acc : acc;                        \
        const float s  = 1.0f / (1.0f + __expf(-zz));                         \
        const float val = (cg == 2) ? 2.0f * s - 1.0f : s;                    \
        const float iv = qperm<QP_BC0>(val);                                  \
        const float fv = qperm<QP_BC1>(val);                                  \
        const float gv = qperm<QP_BC2>(val);                                  \
        const float ov = qperm<QP_BC3>(val);                                  \
        c = fv * c + iv * gv;        /* replicated, bitwise-identical */      \
        const float e2 = __expf(2.0f * c);                                    \
        const float th = 1.0f - 2.0f / (e2 + 1.0f);                           \
        const float h = ov * th;                                              \
        if (cg == 0) {                                                        \
            ebuf[NXT][II + m] = (_Float16)h;                                  \
            outb[(size_t)(T) * HH + m] = h;                                   \
        }                                                                     \
        __syncthreads();                                                      \
    }

    for (int t = 0; t < TT; t += 4) {
        STEP(0, 1, t,     xq0);
        STEP(1, 0, t + 1, xq1);
        STEP(0, 1, t + 2, xq2);
        STEP(1, 0, t + 3, xq3);
    }
#undef STEP
}

extern "C" void kernel_launch(void* const* d_in, const int* in_sizes, int n_in,
                              void* d_out, int out_size, void* d_ws, size_t ws_size,
                              hipStream_t stream) {
    const float* x    = (const float*)d_in[0];
    const float* W_ih = (const float*)d_in[1];
    const float* W_hh = (const float*)d_in[2];
    const float* b_ih = (const float*)d_in[3];
    const float* b_hh = (const float*)d_in[4];
    float* out = (float*)d_out;
    (void)d_ws; (void)ws_size; (void)in_sizes; (void)n_in; (void)out_size;
    hipLaunchKernelGGL(lstm_persist, dim3(BB), dim3(512), 0, stream,
                       x, W_ih, W_hh, b_ih, b_hh, out);
}